// Round 1
// baseline (1658.816 us; speedup 1.0000x reference)
//
#include <hip/hip_runtime.h>

#define N_NODES 100000
#define N_FEAT  1433
#define HID     64
#define NCLS    7

// ---------------- degree histogram ----------------
__global__ __launch_bounds__(256)
void hist_kernel(const int* __restrict__ dst, int* __restrict__ counts, int E) {
    int e = blockIdx.x * 256 + threadIdx.x;
    if (e < E) atomicAdd(&counts[dst[e]], 1);
}

__global__ __launch_bounds__(256)
void dinv_kernel(const int* __restrict__ counts, float* __restrict__ dinv, int n) {
    int i = blockIdx.x * 256 + threadIdx.x;
    if (i < n) dinv[i] = rsqrtf((float)(counts[i] + 1));   // +1 = self loop
}

// ---------------- single-block exclusive scan (100001 offsets) ----------------
__global__ __launch_bounds__(1024)
void scan_kernel(const int* __restrict__ counts, int* __restrict__ offsets,
                 int* __restrict__ cursor, int n) {
    __shared__ int sums[1024];
    int t = threadIdx.x;
    int chunk = (n + 1023) >> 10;
    int beg = t * chunk;
    int end = min(beg + chunk, n);
    int s = 0;
    for (int i = beg; i < end; ++i) s += counts[i];
    sums[t] = s;
    __syncthreads();
    for (int off = 1; off < 1024; off <<= 1) {
        int v = (t >= off) ? sums[t - off] : 0;
        __syncthreads();
        sums[t] += v;
        __syncthreads();
    }
    int run = (t == 0) ? 0 : sums[t - 1];
    for (int i = beg; i < end; ++i) {
        offsets[i] = run; cursor[i] = run;
        run += counts[i];
    }
    if (t == 1023) offsets[n] = run;
}

// ---------------- CSR scatter ----------------
__global__ __launch_bounds__(256)
void scatter_kernel(const int* __restrict__ src, const int* __restrict__ dst,
                    const float* __restrict__ dinv, int* __restrict__ cursor,
                    int* __restrict__ csr_src, float* __restrict__ csr_w, int E) {
    int e = blockIdx.x * 256 + threadIdx.x;
    if (e >= E) return;
    int s = src[e], d = dst[e];
    int pos = atomicAdd(&cursor[d], 1);
    csr_src[pos] = s;
    csr_w[pos]   = dinv[s] * dinv[d];
}

// ---------------- GEMM1: [M,1433] @ [1433,64], f32, 64x64x32 tile ----------------
__global__ __launch_bounds__(256)
void gemm_xw(const float* __restrict__ X, const float* __restrict__ W,
             float* __restrict__ H, int M, int K) {
    __shared__ __align__(16) float As[32][68];   // k-major, stride 68 keeps 16B align, banks spread
    __shared__ __align__(16) float Bs[32][64];
    int m0  = blockIdx.x * 64;
    int tid = threadIdx.x;
    int tx = tid & 15, ty = tid >> 4;
    int kA = tid & 31, mA0 = tid >> 5;          // A-load: lanes sweep k (coalesced 128B/row)
    int nB = (tid & 15) << 2, kB0 = tid >> 4;   // B-load: float4 along n (coalesced)
    float acc[4][4] = {};
    for (int k0 = 0; k0 < K; k0 += 32) {
#pragma unroll
        for (int i = 0; i < 8; ++i) {
            int m = mA0 + i * 8;
            int row = m0 + m, kk = k0 + kA;
            float v = 0.f;
            if (row < M && kk < K) v = X[(size_t)row * K + kk];
            As[kA][m] = v;
        }
#pragma unroll
        for (int i = 0; i < 2; ++i) {
            int kk = k0 + kB0 + i * 16;
            float4 v = make_float4(0.f, 0.f, 0.f, 0.f);
            if (kk < K) v = *(const float4*)&W[(size_t)kk * 64 + nB];
            *(float4*)&Bs[kB0 + i * 16][nB] = v;
        }
        __syncthreads();
#pragma unroll
        for (int k = 0; k < 32; ++k) {
            float4 a4 = *(const float4*)&As[k][ty << 2];
            float4 b4 = *(const float4*)&Bs[k][tx << 2];
            float aa[4] = {a4.x, a4.y, a4.z, a4.w};
            float bb[4] = {b4.x, b4.y, b4.z, b4.w};
#pragma unroll
            for (int i = 0; i < 4; ++i)
#pragma unroll
                for (int j = 0; j < 4; ++j)
                    acc[i][j] = fmaf(aa[i], bb[j], acc[i][j]);
        }
        __syncthreads();
    }
#pragma unroll
    for (int i = 0; i < 4; ++i) {
        int row = m0 + (ty << 2) + i;
        if (row < M) {
            float4 o = make_float4(acc[i][0], acc[i][1], acc[i][2], acc[i][3]);
            *(float4*)&H[(size_t)row * 64 + (tx << 2)] = o;
        }
    }
}

// ---------------- gather-aggregate: one wave per node, lane = feature ----------------
__global__ __launch_bounds__(256)
void aggregate_kernel(const float* __restrict__ h, const int* __restrict__ csr_src,
                      const float* __restrict__ csr_w, const int* __restrict__ offsets,
                      const float* __restrict__ dinv, const float* __restrict__ bias,
                      float* __restrict__ out, int n) {
    int wave = (blockIdx.x * blockDim.x + threadIdx.x) >> 6;
    int lane = threadIdx.x & 63;
    if (wave >= n) return;
    float di  = dinv[wave];
    float acc = h[(size_t)wave * HID + lane] * di * di;   // self loop
    int beg = offsets[wave], end = offsets[wave + 1];
    for (int e = beg; e < end; ++e) {
        int   s = csr_src[e];
        float w = csr_w[e];
        acc = fmaf(h[(size_t)s * HID + lane], w, acc);
    }
    out[(size_t)wave * HID + lane] = fmaxf(acc + bias[lane], 0.f);
}

// ---------------- GEMM2: [M,64] @ [64,64], wave per row ----------------
__global__ __launch_bounds__(256)
void gemm64_kernel(const float* __restrict__ A, const float* __restrict__ W,
                   float* __restrict__ out, int M) {
    __shared__ float Ws[64 * 64];
    for (int i = threadIdx.x; i < 64 * 64; i += 256) Ws[i] = W[i];
    __syncthreads();
    int wave = (blockIdx.x * blockDim.x + threadIdx.x) >> 6;
    int lane = threadIdx.x & 63;
    if (wave >= M) return;
    const float* a = A + (size_t)wave * 64;
    float acc = 0.f;
#pragma unroll
    for (int k = 0; k < 64; ++k) acc = fmaf(a[k], Ws[k * 64 + lane], acc);
    out[(size_t)wave * 64 + lane] = acc;
}

// ---------------- fused MLP head + log_softmax: wave per node ----------------
__global__ __launch_bounds__(256)
void mlp_kernel(const float* __restrict__ y,
                const float* __restrict__ Wf1, const float* __restrict__ bf1,
                const float* __restrict__ Wf2, const float* __restrict__ bf2,
                const float* __restrict__ Wf3, const float* __restrict__ bf3,
                float* __restrict__ out, int M) {
    __shared__ float W1s[64 * 64];
    __shared__ float W2s[64 * 64];
    __shared__ float W3s[64 * NCLS];
    __shared__ float b1s[64], b2s[64], b3s[NCLS];
    __shared__ float vbuf[4][64];
    __shared__ float zbuf[4][8];
    int tid = threadIdx.x;
    for (int i = tid; i < 4096; i += 256) { W1s[i] = Wf1[i]; W2s[i] = Wf2[i]; }
    for (int i = tid; i < 64 * NCLS; i += 256) W3s[i] = Wf3[i];
    if (tid < 64) { b1s[tid] = bf1[tid]; b2s[tid] = bf2[tid]; }
    if (tid < NCLS) b3s[tid] = bf3[tid];
    __syncthreads();
    int w = tid >> 6, lane = tid & 63;
    int node = blockIdx.x * 4 + w;
    if (node >= M) return;

    // layer f1
    vbuf[w][lane] = y[(size_t)node * 64 + lane];
    float u = b1s[lane];
#pragma unroll
    for (int k = 0; k < 64; ++k) u = fmaf(vbuf[w][k], W1s[k * 64 + lane], u);
    u = fmaxf(u, 0.f);
    // layer f2 (wave-lockstep: prior reads complete before this store issues)
    vbuf[w][lane] = u;
    float u2 = b2s[lane];
#pragma unroll
    for (int k = 0; k < 64; ++k) u2 = fmaf(vbuf[w][k], W2s[k * 64 + lane], u2);
    u2 = fmaxf(u2, 0.f);
    // layer f3 (7 outputs)
    vbuf[w][lane] = u2;
    float z = 0.f;
    if (lane < NCLS) {
        z = b3s[lane];
#pragma unroll
        for (int k = 0; k < 64; ++k) z = fmaf(vbuf[w][k], W3s[k * NCLS + lane], z);
    }
    if (lane < 8)    zbuf[w][lane] = -1e30f;
    if (lane < NCLS) zbuf[w][lane] = z;
    float m = -1e30f;
#pragma unroll
    for (int j = 0; j < NCLS; ++j) m = fmaxf(m, zbuf[w][j]);
    float ssum = 0.f;
#pragma unroll
    for (int j = 0; j < NCLS; ++j) ssum += expf(zbuf[w][j] - m);
    float lse = m + logf(ssum);
    if (lane < NCLS) out[(size_t)node * NCLS + lane] = z - lse;
}

extern "C" void kernel_launch(void* const* d_in, const int* in_sizes, int n_in,
                              void* d_out, int out_size, void* d_ws, size_t ws_size,
                              hipStream_t stream) {
    const float* x   = (const float*)d_in[0];
    const int*   ei  = (const int*)d_in[1];
    const float* W1  = (const float*)d_in[2];
    const float* b1  = (const float*)d_in[3];
    const float* W2  = (const float*)d_in[4];
    const float* b2  = (const float*)d_in[5];
    const float* Wf1 = (const float*)d_in[6];
    const float* bf1 = (const float*)d_in[7];
    const float* Wf2 = (const float*)d_in[8];
    const float* bf2 = (const float*)d_in[9];
    const float* Wf3 = (const float*)d_in[10];
    const float* bf3 = (const float*)d_in[11];

    const int N = N_NODES;
    const int E = in_sizes[1] / 2;
    const int K = N_FEAT;
    float* outp = (float*)d_out;

    char* p = (char*)d_ws;
    auto alloc = [&](size_t bytes) {
        char* q = p;
        p += (bytes + 255) & ~(size_t)255;
        return q;
    };
    int*   counts  = (int*)  alloc((size_t)N * 4);
    int*   offsets = (int*)  alloc((size_t)(N + 1) * 4);
    int*   cursor  = (int*)  alloc((size_t)N * 4);
    float* dinv    = (float*)alloc((size_t)N * 4);
    int*   csr_src = (int*)  alloc((size_t)E * 4);
    float* csr_w   = (float*)alloc((size_t)E * 4);
    float* bufA    = (float*)alloc((size_t)N * HID * 4);
    float* bufB    = (float*)alloc((size_t)N * HID * 4);

    const int* src = ei;
    const int* dst = ei + E;

    hipMemsetAsync(counts, 0, (size_t)N * 4, stream);
    int ge = (E + 255) / 256;
    hist_kernel<<<ge, 256, 0, stream>>>(dst, counts, E);
    dinv_kernel<<<(N + 255) / 256, 256, 0, stream>>>(counts, dinv, N);
    scan_kernel<<<1, 1024, 0, stream>>>(counts, offsets, cursor, N);
    scatter_kernel<<<ge, 256, 0, stream>>>(src, dst, dinv, cursor, csr_src, csr_w, E);

    gemm_xw<<<(N + 63) / 64, 256, 0, stream>>>(x, W1, bufA, N, K);
    aggregate_kernel<<<(N + 3) / 4, 256, 0, stream>>>(bufA, csr_src, csr_w, offsets, dinv, b1, bufB, N);
    gemm64_kernel<<<(N + 3) / 4, 256, 0, stream>>>(bufB, W2, bufA, N);
    aggregate_kernel<<<(N + 3) / 4, 256, 0, stream>>>(bufA, csr_src, csr_w, offsets, dinv, b2, bufB, N);
    mlp_kernel<<<(N + 3) / 4, 256, 0, stream>>>(bufB, Wf1, bf1, Wf2, bf2, Wf3, bf3, outp, N);
}

// Round 2
// 1488.728 us; speedup vs baseline: 1.1143x; 1.1143x over previous
//
#include <hip/hip_runtime.h>

#define N_NODES 100000
#define N_FEAT  1433
#define KP      1472     // N_FEAT padded to 23*64
#define NKSTEP  23
#define HID     64
#define NCLS    7

typedef __attribute__((ext_vector_type(8))) short short8v;
typedef __attribute__((ext_vector_type(4))) float f32x4;

__device__ __forceinline__ unsigned short f2bf(float v) {
    unsigned u = __float_as_uint(v);
    unsigned r = (u + 0x7FFFu + ((u >> 16) & 1u)) >> 16;   // RNE
    return (unsigned short)r;
}
__device__ __forceinline__ float bf2f(unsigned short h) {
    return __uint_as_float(((unsigned)h) << 16);
}

// ---------------- degree histogram ----------------
__global__ __launch_bounds__(256)
void hist_kernel(const int* __restrict__ dst, int* __restrict__ counts, int E) {
    int e = blockIdx.x * 256 + threadIdx.x;
    if (e < E) atomicAdd(&counts[dst[e]], 1);
}

__global__ __launch_bounds__(256)
void dinv_kernel(const int* __restrict__ counts, float* __restrict__ dinv, int n) {
    int i = blockIdx.x * 256 + threadIdx.x;
    if (i < n) dinv[i] = rsqrtf((float)(counts[i] + 1));   // +1 = self loop
}

// ---------------- single-block exclusive scan ----------------
__global__ __launch_bounds__(1024)
void scan_kernel(const int* __restrict__ counts, int* __restrict__ offsets,
                 int* __restrict__ cursor, int n) {
    __shared__ int sums[1024];
    int t = threadIdx.x;
    int chunk = (n + 1023) >> 10;
    int beg = t * chunk;
    int end = min(beg + chunk, n);
    int s = 0;
    for (int i = beg; i < end; ++i) s += counts[i];
    sums[t] = s;
    __syncthreads();
    for (int off = 1; off < 1024; off <<= 1) {
        int v = (t >= off) ? sums[t - off] : 0;
        __syncthreads();
        sums[t] += v;
        __syncthreads();
    }
    int run = (t == 0) ? 0 : sums[t - 1];
    for (int i = beg; i < end; ++i) {
        offsets[i] = run; cursor[i] = run;
        run += counts[i];
    }
    if (t == 1023) offsets[n] = run;
}

// ---------------- CSR scatter ----------------
__global__ __launch_bounds__(256)
void scatter_kernel(const int* __restrict__ src, const int* __restrict__ dst,
                    const float* __restrict__ dinv, int* __restrict__ cursor,
                    int* __restrict__ csr_src, float* __restrict__ csr_w, int E) {
    int e = blockIdx.x * 256 + threadIdx.x;
    if (e >= E) return;
    int s = src[e], d = dst[e];
    int pos = atomicAdd(&cursor[d], 1);
    csr_src[pos] = s;
    csr_w[pos]   = dinv[s] * dinv[d];
}

// ---------------- W1 transpose + bf16 hi/lo split: [1433,64] -> [64,KP] ----------------
__global__ __launch_bounds__(256)
void convert_w(const float* __restrict__ W,
               unsigned short* __restrict__ wt_hi, unsigned short* __restrict__ wt_lo) {
    int idx = blockIdx.x * 256 + threadIdx.x;   // over KP*64
    if (idx >= KP * 64) return;
    int k = idx >> 6, n = idx & 63;
    float v = (k < N_FEAT) ? W[(size_t)k * 64 + n] : 0.f;
    unsigned short h = f2bf(v);
    wt_hi[(size_t)n * KP + k] = h;
    wt_lo[(size_t)n * KP + k] = f2bf(v - bf2f(h));
}

// ---------------- GEMM1: [M,1433]@[1433,64] via bf16x3 MFMA, 128x64 tile ----------------
__global__ __launch_bounds__(256)
void gemm_xw_mfma(const float* __restrict__ X,
                  const unsigned short* __restrict__ wt_hi,
                  const unsigned short* __restrict__ wt_lo,
                  float* __restrict__ H, int M) {
    __shared__ __align__(16) unsigned short AsH[128 * 64];
    __shared__ __align__(16) unsigned short AsL[128 * 64];
    __shared__ __align__(16) unsigned short BsH[64 * 64];
    __shared__ __align__(16) unsigned short BsL[64 * 64];
    char* asH = (char*)AsH; char* asL = (char*)AsL;
    char* bsH = (char*)BsH; char* bsL = (char*)BsL;

    const int t    = threadIdx.x;
    const int m0   = blockIdx.x * 128;
    const int lane = t & 63;
    const int w    = t >> 6;

    f32x4 acc[2][4];
#pragma unroll
    for (int i = 0; i < 2; ++i)
#pragma unroll
        for (int j = 0; j < 4; ++j) acc[i][j] = (f32x4){0.f, 0.f, 0.f, 0.f};

    for (int k0 = 0; k0 < KP; k0 += 64) {
        // ---- stage A: 128 rows x 64 k, f32 -> bf16 hi/lo, swizzled ----
#pragma unroll
        for (int p = 0; p < 16; ++p) {
            int id  = p * 256 + t;       // 0..4095
            int row = id >> 5;           // 0..127
            int kp  = id & 31;           // k-pair index
            int grow = m0 + row;
            int k = k0 + kp * 2;
            float v0 = 0.f, v1 = 0.f;
            if (grow < M) {
                if (k < N_FEAT)     v0 = X[(size_t)grow * N_FEAT + k];
                if (k + 1 < N_FEAT) v1 = X[(size_t)grow * N_FEAT + k + 1];
            }
            unsigned short h0 = f2bf(v0), h1 = f2bf(v1);
            unsigned hi = (unsigned)h0 | ((unsigned)h1 << 16);
            unsigned lo = (unsigned)f2bf(v0 - bf2f(h0)) |
                          ((unsigned)f2bf(v1 - bf2f(h1)) << 16);
            int byte = (row * 128 + kp * 4) ^ ((row & 7) << 4);
            *(unsigned*)(asH + byte) = hi;
            *(unsigned*)(asL + byte) = lo;
        }
        // ---- stage B: 64 n x 64 k from pre-split wt, swizzled ----
#pragma unroll
        for (int p = 0; p < 2; ++p) {
            int id = p * 256 + t;        // 0..511
            int n = id >> 3, k8 = id & 7;
            size_t g = (size_t)n * KP + k0 + k8 * 8;
            uint4 vh = *(const uint4*)(wt_hi + g);
            uint4 vl = *(const uint4*)(wt_lo + g);
            int byte = (n * 128 + k8 * 16) ^ ((n & 7) << 4);
            *(uint4*)(bsH + byte) = vh;
            *(uint4*)(bsL + byte) = vl;
        }
        __syncthreads();
        // ---- compute: wave w owns rows [w*32, w*32+32) ----
#pragma unroll
        for (int kf = 0; kf < 2; ++kf) {
            int kb = kf * 64 + ((lane >> 4) << 4);   // byte offset of k in row
            short8v aH[2], aL[2], bH[4], bL[4];
#pragma unroll
            for (int mf = 0; mf < 2; ++mf) {
                int row = w * 32 + mf * 16 + (lane & 15);
                int byte = (row * 128 + kb) ^ ((row & 7) << 4);
                aH[mf] = *(short8v*)(asH + byte);
                aL[mf] = *(short8v*)(asL + byte);
            }
#pragma unroll
            for (int nf = 0; nf < 4; ++nf) {
                int n = nf * 16 + (lane & 15);
                int byte = (n * 128 + kb) ^ ((n & 7) << 4);
                bH[nf] = *(short8v*)(bsH + byte);
                bL[nf] = *(short8v*)(bsL + byte);
            }
#pragma unroll
            for (int mf = 0; mf < 2; ++mf)
#pragma unroll
                for (int nf = 0; nf < 4; ++nf) {
                    acc[mf][nf] = __builtin_amdgcn_mfma_f32_16x16x32_bf16(aH[mf], bH[nf], acc[mf][nf], 0, 0, 0);
                    acc[mf][nf] = __builtin_amdgcn_mfma_f32_16x16x32_bf16(aL[mf], bH[nf], acc[mf][nf], 0, 0, 0);
                    acc[mf][nf] = __builtin_amdgcn_mfma_f32_16x16x32_bf16(aH[mf], bL[nf], acc[mf][nf], 0, 0, 0);
                }
        }
        __syncthreads();
    }
    // C write: col = lane&15, row = (lane>>4)*4 + reg  [HW-verified layout]
#pragma unroll
    for (int mf = 0; mf < 2; ++mf)
#pragma unroll
        for (int r = 0; r < 4; ++r) {
            int row = m0 + w * 32 + mf * 16 + ((lane >> 4) << 2) + r;
            if (row < M) {
#pragma unroll
                for (int nf = 0; nf < 4; ++nf)
                    H[(size_t)row * 64 + nf * 16 + (lane & 15)] = acc[mf][nf][r];
            }
        }
}

// ---------------- gather-aggregate: one wave per node, lane = feature ----------------
__global__ __launch_bounds__(256)
void aggregate_kernel(const float* __restrict__ h, const int* __restrict__ csr_src,
                      const float* __restrict__ csr_w, const int* __restrict__ offsets,
                      const float* __restrict__ dinv, const float* __restrict__ bias,
                      float* __restrict__ out, int n) {
    int wave = (blockIdx.x * blockDim.x + threadIdx.x) >> 6;
    int lane = threadIdx.x & 63;
    if (wave >= n) return;
    float di  = dinv[wave];
    float acc = h[(size_t)wave * HID + lane] * di * di;   // self loop
    int e = offsets[wave], end = offsets[wave + 1];
    for (; e + 4 <= end; e += 4) {                        // 4-deep load pipeline
        int   s0 = csr_src[e],   s1 = csr_src[e+1], s2 = csr_src[e+2], s3 = csr_src[e+3];
        float w0 = csr_w[e],     w1 = csr_w[e+1],   w2 = csr_w[e+2],   w3 = csr_w[e+3];
        float h0 = h[(size_t)s0 * HID + lane];
        float h1 = h[(size_t)s1 * HID + lane];
        float h2 = h[(size_t)s2 * HID + lane];
        float h3 = h[(size_t)s3 * HID + lane];
        acc = fmaf(h0, w0, acc); acc = fmaf(h1, w1, acc);
        acc = fmaf(h2, w2, acc); acc = fmaf(h3, w3, acc);
    }
    for (; e < end; ++e)
        acc = fmaf(h[(size_t)csr_src[e] * HID + lane], csr_w[e], acc);
    out[(size_t)wave * HID + lane] = fmaxf(acc + bias[lane], 0.f);
}

// ---------------- GEMM2: [M,64] @ [64,64], wave per row ----------------
__global__ __launch_bounds__(256)
void gemm64_kernel(const float* __restrict__ A, const float* __restrict__ W,
                   float* __restrict__ out, int M) {
    __shared__ float Ws[64 * 64];
    for (int i = threadIdx.x; i < 64 * 64; i += 256) Ws[i] = W[i];
    __syncthreads();
    int wave = (blockIdx.x * blockDim.x + threadIdx.x) >> 6;
    int lane = threadIdx.x & 63;
    if (wave >= M) return;
    const float* a = A + (size_t)wave * 64;
    float acc = 0.f;
#pragma unroll
    for (int k = 0; k < 64; ++k) acc = fmaf(a[k], Ws[k * 64 + lane], acc);
    out[(size_t)wave * 64 + lane] = acc;
}

// ---------------- fused MLP head + log_softmax: wave per node ----------------
__global__ __launch_bounds__(256)
void mlp_kernel(const float* __restrict__ y,
                const float* __restrict__ Wf1, const float* __restrict__ bf1,
                const float* __restrict__ Wf2, const float* __restrict__ bf2,
                const float* __restrict__ Wf3, const float* __restrict__ bf3,
                float* __restrict__ out, int M) {
    __shared__ float W1s[64 * 64];
    __shared__ float W2s[64 * 64];
    __shared__ float W3s[64 * NCLS];
    __shared__ float b1s[64], b2s[64], b3s[NCLS];
    __shared__ float vbuf[4][64];
    __shared__ float zbuf[4][8];
    int tid = threadIdx.x;
    for (int i = tid; i < 4096; i += 256) { W1s[i] = Wf1[i]; W2s[i] = Wf2[i]; }
    for (int i = tid; i < 64 * NCLS; i += 256) W3s[i] = Wf3[i];
    if (tid < 64) { b1s[tid] = bf1[tid]; b2s[tid] = bf2[tid]; }
    if (tid < NCLS) b3s[tid] = bf3[tid];
    __syncthreads();
    int w = tid >> 6, lane = tid & 63;
    int node = blockIdx.x * 4 + w;
    if (node >= M) return;

    vbuf[w][lane] = y[(size_t)node * 64 + lane];
    float u = b1s[lane];
#pragma unroll
    for (int k = 0; k < 64; ++k) u = fmaf(vbuf[w][k], W1s[k * 64 + lane], u);
    u = fmaxf(u, 0.f);
    vbuf[w][lane] = u;
    float u2 = b2s[lane];
#pragma unroll
    for (int k = 0; k < 64; ++k) u2 = fmaf(vbuf[w][k], W2s[k * 64 + lane], u2);
    u2 = fmaxf(u2, 0.f);
    vbuf[w][lane] = u2;
    float z = 0.f;
    if (lane < NCLS) {
        z = b3s[lane];
#pragma unroll
        for (int k = 0; k < 64; ++k) z = fmaf(vbuf[w][k], W3s[k * NCLS + lane], z);
    }
    if (lane < 8)    zbuf[w][lane] = -1e30f;
    if (lane < NCLS) zbuf[w][lane] = z;
    float m = -1e30f;
#pragma unroll
    for (int j = 0; j < NCLS; ++j) m = fmaxf(m, zbuf[w][j]);
    float ssum = 0.f;
#pragma unroll
    for (int j = 0; j < NCLS; ++j) ssum += expf(zbuf[w][j] - m);
    float lse = m + logf(ssum);
    if (lane < NCLS) out[(size_t)node * NCLS + lane] = z - lse;
}

extern "C" void kernel_launch(void* const* d_in, const int* in_sizes, int n_in,
                              void* d_out, int out_size, void* d_ws, size_t ws_size,
                              hipStream_t stream) {
    const float* x   = (const float*)d_in[0];
    const int*   ei  = (const int*)d_in[1];
    const float* W1  = (const float*)d_in[2];
    const float* b1  = (const float*)d_in[3];
    const float* W2  = (const float*)d_in[4];
    const float* b2  = (const float*)d_in[5];
    const float* Wf1 = (const float*)d_in[6];
    const float* bf1 = (const float*)d_in[7];
    const float* Wf2 = (const float*)d_in[8];
    const float* bf2 = (const float*)d_in[9];
    const float* Wf3 = (const float*)d_in[10];
    const float* bf3 = (const float*)d_in[11];

    const int N = N_NODES;
    const int E = in_sizes[1] / 2;
    float* outp = (float*)d_out;

    char* p = (char*)d_ws;
    auto alloc = [&](size_t bytes) {
        char* q = p;
        p += (bytes + 255) & ~(size_t)255;
        return q;
    };
    int*            counts  = (int*)           alloc((size_t)N * 4);
    int*            offsets = (int*)           alloc((size_t)(N + 1) * 4);
    int*            cursor  = (int*)           alloc((size_t)N * 4);
    float*          dinv    = (float*)         alloc((size_t)N * 4);
    int*            csr_src = (int*)           alloc((size_t)E * 4);
    float*          csr_w   = (float*)         alloc((size_t)E * 4);
    float*          bufA    = (float*)         alloc((size_t)N * HID * 4);
    float*          bufB    = (float*)         alloc((size_t)N * HID * 4);
    unsigned short* wt_hi   = (unsigned short*)alloc((size_t)64 * KP * 2);
    unsigned short* wt_lo   = (unsigned short*)alloc((size_t)64 * KP * 2);

    const int* src = ei;
    const int* dst = ei + E;

    hipMemsetAsync(counts, 0, (size_t)N * 4, stream);
    int ge = (E + 255) / 256;
    hist_kernel<<<ge, 256, 0, stream>>>(dst, counts, E);
    dinv_kernel<<<(N + 255) / 256, 256, 0, stream>>>(counts, dinv, N);
    scan_kernel<<<1, 1024, 0, stream>>>(counts, offsets, cursor, N);
    scatter_kernel<<<ge, 256, 0, stream>>>(src, dst, dinv, cursor, csr_src, csr_w, E);

    convert_w<<<(KP * 64 + 255) / 256, 256, 0, stream>>>(W1, wt_hi, wt_lo);
    gemm_xw_mfma<<<(N + 127) / 128, 256, 0, stream>>>(x, wt_hi, wt_lo, bufA, N);
    aggregate_kernel<<<(N + 3) / 4, 256, 0, stream>>>(bufA, csr_src, csr_w, offsets, dinv, b1, bufB, N);
    gemm64_kernel<<<(N + 3) / 4, 256, 0, stream>>>(bufB, W2, bufA, N);
    aggregate_kernel<<<(N + 3) / 4, 256, 0, stream>>>(bufA, csr_src, csr_w, offsets, dinv, b2, bufB, N);
    mlp_kernel<<<(N + 3) / 4, 256, 0, stream>>>(bufB, Wf1, bf1, Wf2, bf2, Wf3, bf3, outp, N);
}